// Round 1
// baseline (1143.954 us; speedup 1.0000x reference)
//
#include <hip/hip_runtime.h>
#include <hip/hip_bf16.h>
#include <stdint.h>

typedef __attribute__((ext_vector_type(8))) short short8;
typedef __attribute__((ext_vector_type(8))) unsigned short ushort8;
typedef __attribute__((ext_vector_type(4))) float f32x4;

#define K_DIM 4096
#define N_DIM 11008
#define M_DIM 8192
#define BM 128
#define BN 128
#define BK 64

__constant__ float c_nf4[16] = {
    -1.0f, -0.6961928009986877f, -0.5250730514526367f, -0.39491748809814453f,
    -0.28444138169288635f, -0.18477343022823334f, -0.09105003625154495f, 0.0f,
    0.07958029955625534f, 0.16093020141124725f, 0.24611230194568634f,
    0.33791524171829224f, 0.44070982933044434f, 0.5626170039176941f,
    0.7229568362236023f, 1.0f};

__device__ __forceinline__ unsigned short f2bf(float f) {
    uint32_t u = __float_as_uint(f);
    u += 0x7fffu + ((u >> 16) & 1u);   // round-to-nearest-even (finite inputs)
    return (unsigned short)(u >> 16);
}

// One thread handles 8 consecutive elements (all within one 64-elem absmax block).
__global__ __launch_bounds__(256) void nf4_dequant_w(const int* __restrict__ q,
                                                     const float* __restrict__ absmax,
                                                     unsigned short* __restrict__ w) {
    __shared__ float lut[16];
    if (threadIdx.x < 16) lut[threadIdx.x] = c_nf4[threadIdx.x];
    __syncthreads();
    size_t t = (size_t)blockIdx.x * 256 + threadIdx.x;
    const int4* q4 = (const int4*)q;
    int4 qa = q4[2 * t];
    int4 qb = q4[2 * t + 1];
    float s = absmax[t >> 3];   // (t*8)/64
    ushort8 o;
    o[0] = f2bf(lut[qa.x & 15] * s);
    o[1] = f2bf(lut[qa.y & 15] * s);
    o[2] = f2bf(lut[qa.z & 15] * s);
    o[3] = f2bf(lut[qa.w & 15] * s);
    o[4] = f2bf(lut[qb.x & 15] * s);
    o[5] = f2bf(lut[qb.y & 15] * s);
    o[6] = f2bf(lut[qb.z & 15] * s);
    o[7] = f2bf(lut[qb.w & 15] * s);
    ((ushort8*)w)[t] = o;
}

__global__ __launch_bounds__(256) void x_to_bf16(const float* __restrict__ x,
                                                 unsigned short* __restrict__ xb) {
    size_t t = (size_t)blockIdx.x * 256 + threadIdx.x;
    const float4* x4 = (const float4*)x;
    float4 a = x4[2 * t];
    float4 b = x4[2 * t + 1];
    ushort8 o;
    o[0] = f2bf(a.x); o[1] = f2bf(a.y); o[2] = f2bf(a.z); o[3] = f2bf(a.w);
    o[4] = f2bf(b.x); o[5] = f2bf(b.y); o[6] = f2bf(b.z); o[7] = f2bf(b.w);
    ((ushort8*)xb)[t] = o;
}

// m97-structure GEMM: C[M][N] = A[M][K] * B[N][K]^T + bias, bf16 in / f32 out.
// 128x128 tile, BK=64, 4 waves (2x2), 4x4 16x16x32 frags per wave,
// global_load_lds width-16 staging, 2-barrier K-loop.
__global__ __launch_bounds__(256) void gemm_bf16_bt(const unsigned short* __restrict__ A,
                                                    const unsigned short* __restrict__ B,
                                                    const float* __restrict__ bias,
                                                    float* __restrict__ C) {
    __shared__ unsigned short As[BM * BK];   // 16 KB
    __shared__ unsigned short Bs[BN * BK];   // 16 KB

    const int tid  = threadIdx.x;
    const int wave = tid >> 6;
    const int lane = tid & 63;

    // XCD-aware bijective swizzle: gridDim.x = 5504, 5504 % 8 == 0.
    const int nbn = N_DIM / BN;               // 86
    const int cpx = (int)gridDim.x >> 3;      // 688
    const int bid = (int)blockIdx.x;
    const int swz = (bid & 7) * cpx + (bid >> 3);
    const int bm = swz / nbn;
    const int bn = swz % nbn;

    const int wm = wave >> 1;                 // 0..1
    const int wn = wave & 1;                  // 0..1
    const int lr = lane & 15;                 // fragment row/col
    const int lk = (lane >> 4) << 3;          // k sub-offset: 0,8,16,24

    f32x4 acc[4][4];
#pragma unroll
    for (int i = 0; i < 4; ++i)
#pragma unroll
        for (int j = 0; j < 4; ++j)
#pragma unroll
            for (int r = 0; r < 4; ++r) acc[i][j][r] = 0.0f;

    const unsigned short* Abase = A + (size_t)bm * BM * K_DIM;
    const unsigned short* Bbase = B + (size_t)bn * BN * K_DIM;

    for (int kt = 0; kt < K_DIM / BK; ++kt) {
        const int k0 = kt * BK;
        // Stage A tile: 128 rows x 128 B, 1024 16B-chunks, 4 issues x 256 thr.
#pragma unroll
        for (int it = 0; it < 4; ++it) {
            const int c = it * 256 + tid;           // chunk index
            const int row = c >> 3;
            const int cc = (c & 7) << 3;            // element col within BK
            __builtin_amdgcn_global_load_lds(
                (const __attribute__((address_space(1))) void*)(Abase + (size_t)row * K_DIM + k0 + cc),
                (__attribute__((address_space(3))) void*)(As + (size_t)(it * 256 + wave * 64) * 8),
                16, 0, 0);
        }
#pragma unroll
        for (int it = 0; it < 4; ++it) {
            const int c = it * 256 + tid;
            const int row = c >> 3;
            const int cc = (c & 7) << 3;
            __builtin_amdgcn_global_load_lds(
                (const __attribute__((address_space(1))) void*)(Bbase + (size_t)row * K_DIM + k0 + cc),
                (__attribute__((address_space(3))) void*)(Bs + (size_t)(it * 256 + wave * 64) * 8),
                16, 0, 0);
        }
        __syncthreads();   // drains vmcnt before barrier (compiler-inserted)

#pragma unroll
        for (int kk = 0; kk < BK; kk += 32) {
            short8 af[4], bf[4];
#pragma unroll
            for (int mi = 0; mi < 4; ++mi)
                af[mi] = *(const short8*)(As + (wm * 64 + mi * 16 + lr) * BK + kk + lk);
#pragma unroll
            for (int ni = 0; ni < 4; ++ni)
                bf[ni] = *(const short8*)(Bs + (wn * 64 + ni * 16 + lr) * BK + kk + lk);
#pragma unroll
            for (int mi = 0; mi < 4; ++mi)
#pragma unroll
                for (int ni = 0; ni < 4; ++ni)
                    acc[mi][ni] = __builtin_amdgcn_mfma_f32_16x16x32_bf16(
                        af[mi], bf[ni], acc[mi][ni], 0, 0, 0);
        }
        __syncthreads();
    }

    // Epilogue. C/D layout (verified m89/m91): col = lane&15, row = (lane>>4)*4 + r.
    const int row0 = bm * BM + wm * 64 + ((lane >> 4) << 2);
    const int col0 = bn * BN + wn * 64 + lr;
#pragma unroll
    for (int ni = 0; ni < 4; ++ni) {
        const int col = col0 + ni * 16;
        const float bv = bias[col];
#pragma unroll
        for (int mi = 0; mi < 4; ++mi) {
#pragma unroll
            for (int r = 0; r < 4; ++r) {
                C[(size_t)(row0 + mi * 16 + r) * N_DIM + col] = acc[mi][ni][r] + bv;
            }
        }
    }
}

extern "C" void kernel_launch(void* const* d_in, const int* in_sizes, int n_in,
                              void* d_out, int out_size, void* d_ws, size_t ws_size,
                              hipStream_t stream) {
    const float* x    = (const float*)d_in[0];   // [4,2048,4096] f32
    const int*   wq   = (const int*)d_in[1];     // [11008,4096] int32 in 0..15
    const float* am   = (const float*)d_in[2];   // [11008,64] f32
    const float* bias = (const float*)d_in[3];   // [11008] f32
    float* out = (float*)d_out;                  // [4,2048,11008] f32

    const size_t w_elems = (size_t)N_DIM * K_DIM;       // 45,088,768
    const size_t x_elems = (size_t)M_DIM * K_DIM;       // 33,554,432
    const size_t need = (w_elems + x_elems) * sizeof(unsigned short);
    if (ws_size < need) return;  // workspace too small — fail validation, not memory

    unsigned short* wbf = (unsigned short*)d_ws;
    unsigned short* xbf = wbf + w_elems;

    nf4_dequant_w<<<(int)(w_elems / 8 / 256), 256, 0, stream>>>(wq, am, wbf);
    x_to_bf16<<<(int)(x_elems / 8 / 256), 256, 0, stream>>>(x, xbf);

    const int grid = (M_DIM / BM) * (N_DIM / BN);   // 64*86 = 5504
    gemm_bf16_bt<<<grid, 256, 0, stream>>>(xbf, wbf, bias, out);
}

// Round 2
// 932.141 us; speedup vs baseline: 1.2272x; 1.2272x over previous
//
#include <hip/hip_runtime.h>
#include <hip/hip_bf16.h>
#include <stdint.h>

typedef __attribute__((ext_vector_type(8))) short short8;
typedef __attribute__((ext_vector_type(8))) unsigned short ushort8;
typedef __attribute__((ext_vector_type(4))) float f32x4;

#define K_DIM 4096
#define N_DIM 11008
#define M_DIM 8192
#define BM 256
#define BN 256
#define BK 32
#define TILES (K_DIM / BK)   // 128

__constant__ float c_nf4[16] = {
    -1.0f, -0.6961928009986877f, -0.5250730514526367f, -0.39491748809814453f,
    -0.28444138169288635f, -0.18477343022823334f, -0.09105003625154495f, 0.0f,
    0.07958029955625534f, 0.16093020141124725f, 0.24611230194568634f,
    0.33791524171829224f, 0.44070982933044434f, 0.5626170039176941f,
    0.7229568362236023f, 1.0f};

__device__ __forceinline__ unsigned short f2bf(float f) {
    uint32_t u = __float_as_uint(f);
    u += 0x7fffu + ((u >> 16) & 1u);   // round-to-nearest-even (finite inputs)
    return (unsigned short)(u >> 16);
}

__global__ __launch_bounds__(256) void nf4_dequant_w(const int* __restrict__ q,
                                                     const float* __restrict__ absmax,
                                                     unsigned short* __restrict__ w) {
    __shared__ float lut[16];
    if (threadIdx.x < 16) lut[threadIdx.x] = c_nf4[threadIdx.x];
    __syncthreads();
    size_t t = (size_t)blockIdx.x * 256 + threadIdx.x;
    const int4* q4 = (const int4*)q;
    int4 qa = q4[2 * t];
    int4 qb = q4[2 * t + 1];
    float s = absmax[t >> 3];
    ushort8 o;
    o[0] = f2bf(lut[qa.x & 15] * s);
    o[1] = f2bf(lut[qa.y & 15] * s);
    o[2] = f2bf(lut[qa.z & 15] * s);
    o[3] = f2bf(lut[qa.w & 15] * s);
    o[4] = f2bf(lut[qb.x & 15] * s);
    o[5] = f2bf(lut[qb.y & 15] * s);
    o[6] = f2bf(lut[qb.z & 15] * s);
    o[7] = f2bf(lut[qb.w & 15] * s);
    ((ushort8*)w)[t] = o;
}

__global__ __launch_bounds__(256) void x_to_bf16(const float* __restrict__ x,
                                                 unsigned short* __restrict__ xb) {
    size_t t = (size_t)blockIdx.x * 256 + threadIdx.x;
    const float4* x4 = (const float4*)x;
    float4 a = x4[2 * t];
    float4 b = x4[2 * t + 1];
    ushort8 o;
    o[0] = f2bf(a.x); o[1] = f2bf(a.y); o[2] = f2bf(a.z); o[3] = f2bf(a.w);
    o[4] = f2bf(b.x); o[5] = f2bf(b.y); o[6] = f2bf(b.z); o[7] = f2bf(b.w);
    ((ushort8*)xb)[t] = o;
}

// Stage one 128-row x 32-col half of a [256][32] bf16 tile: 512 threads x 16B.
// LDS dest is wave-uniform base + lane*16 (HW rule); layout is linear [256][32].
#define STAGE(gbase, region, j, k0)                                           \
  do {                                                                        \
    const int _row = (j) * 128 + (tid >> 2);                                  \
    const int _cp = tid & 3;                                                  \
    __builtin_amdgcn_global_load_lds(                                         \
        (const __attribute__((address_space(1))) void*)((gbase) +             \
            (size_t)_row * K_DIM + (k0) + _cp * 8),                           \
        (__attribute__((address_space(3))) void*)((region) +                  \
            ((j) * 512 + wave * 64) * 8),                                     \
        16, 0, 0);                                                            \
  } while (0)

#define MFMA4(mi_, Areg)                                                                  \
  acc[mi_][0] = __builtin_amdgcn_mfma_f32_16x16x32_bf16(Areg, b0, acc[mi_][0], 0, 0, 0);  \
  acc[mi_][1] = __builtin_amdgcn_mfma_f32_16x16x32_bf16(Areg, b1, acc[mi_][1], 0, 0, 0);  \
  acc[mi_][2] = __builtin_amdgcn_mfma_f32_16x16x32_bf16(Areg, b2, acc[mi_][2], 0, 0, 0);  \
  acc[mi_][3] = __builtin_amdgcn_mfma_f32_16x16x32_bf16(Areg, b3, acc[mi_][3], 0, 0, 0);

// 256x256 tile, BK=32, 8 waves (2M x 4N), triple-buffered LDS, counted vmcnt.
// C[M][N] = A[M][K] * B[N][K]^T + bias; bf16 in, f32 out.
__global__ __launch_bounds__(512, 2) void gemm256(const unsigned short* __restrict__ A,
                                                  const unsigned short* __restrict__ B,
                                                  const float* __restrict__ bias,
                                                  float* __restrict__ C) {
    __shared__ unsigned short As[3][BM * BK];   // 3 x 16 KB
    __shared__ unsigned short Bs[3][BN * BK];   // 3 x 16 KB

    const int tid  = threadIdx.x;
    const int wave = tid >> 6;
    const int lane = tid & 63;
    const int wm = wave >> 2;               // 0..1 -> 128-row slab
    const int wn = wave & 3;                // 0..3 -> 64-col slab
    const int lr = lane & 15;
    const int lk = (lane >> 4) << 3;        // 0,8,16,24

    // XCD-aware bijective swizzle: grid = 1376, 1376 % 8 == 0.
    const int nbn = N_DIM / BN;             // 43
    const int cpx = (int)gridDim.x >> 3;    // 172
    const int bid = (int)blockIdx.x;
    const int swz = (bid & 7) * cpx + (bid >> 3);
    const int bm = swz / nbn;
    const int bn = swz % nbn;

    const unsigned short* Ab = A + (size_t)bm * BM * K_DIM;
    const unsigned short* Bb = B + (size_t)bn * BN * K_DIM;

    f32x4 acc[8][4];
#pragma unroll
    for (int i = 0; i < 8; ++i)
#pragma unroll
        for (int j = 0; j < 4; ++j)
#pragma unroll
            for (int v = 0; v < 4; ++v) acc[i][j][v] = 0.0f;

    // Prologue: stage tiles 0 and 1 (8 loads/thread), wait tile 0 landed.
    STAGE(Ab, &As[0][0], 0, 0); STAGE(Bb, &Bs[0][0], 0, 0);
    STAGE(Ab, &As[0][0], 1, 0); STAGE(Bb, &Bs[0][0], 1, 0);
    STAGE(Ab, &As[1][0], 0, BK); STAGE(Bb, &Bs[1][0], 0, BK);
    STAGE(Ab, &As[1][0], 1, BK); STAGE(Bb, &Bs[1][0], 1, BK);
    asm volatile("s_waitcnt vmcnt(4)" ::: "memory");
    asm volatile("s_barrier" ::: "memory");

    int r = 0, r2 = 2;
#pragma unroll 1
    for (int t = 0; t < TILES; ++t) {
        int ts = t + 2; if (ts >= TILES) ts -= TILES;   // wrap: harmless garbage stages at tail
        const int k0s = ts * BK;
        const unsigned short* Ar = &As[r][0];
        const unsigned short* Br = &Bs[r][0];
        unsigned short* Aw = &As[r2][0];
        unsigned short* Bw = &Bs[r2][0];

        // ---------------- phase 1: quadrant mi 0..3 ----------------
        short8 a0 = *(const short8*)(Ar + (wm * 128 +  0 + lr) * BK + lk);
        short8 a1 = *(const short8*)(Ar + (wm * 128 + 16 + lr) * BK + lk);
        short8 a2 = *(const short8*)(Ar + (wm * 128 + 32 + lr) * BK + lk);
        short8 a3 = *(const short8*)(Ar + (wm * 128 + 48 + lr) * BK + lk);
        short8 b0 = *(const short8*)(Br + (wn * 64 +  0 + lr) * BK + lk);
        short8 b1 = *(const short8*)(Br + (wn * 64 + 16 + lr) * BK + lk);
        short8 b2 = *(const short8*)(Br + (wn * 64 + 32 + lr) * BK + lk);
        short8 b3 = *(const short8*)(Br + (wn * 64 + 48 + lr) * BK + lk);
        STAGE(Ab, Aw, 0, k0s);
        STAGE(Bb, Bw, 0, k0s);
        asm volatile("s_barrier" ::: "memory");
        asm volatile("s_waitcnt lgkmcnt(0)" ::: "memory");
        __builtin_amdgcn_sched_barrier(0);
        __builtin_amdgcn_s_setprio(1);
        MFMA4(0, a0) MFMA4(1, a1) MFMA4(2, a2) MFMA4(3, a3)
        __builtin_amdgcn_s_setprio(0);
        __builtin_amdgcn_sched_barrier(0);
        asm volatile("s_barrier" ::: "memory");

        // ---------------- phase 2: quadrant mi 4..7 (reuse b0..b3) --
        a0 = *(const short8*)(Ar + (wm * 128 +  64 + lr) * BK + lk);
        a1 = *(const short8*)(Ar + (wm * 128 +  80 + lr) * BK + lk);
        a2 = *(const short8*)(Ar + (wm * 128 +  96 + lr) * BK + lk);
        a3 = *(const short8*)(Ar + (wm * 128 + 112 + lr) * BK + lk);
        STAGE(Ab, Aw, 1, k0s);
        STAGE(Bb, Bw, 1, k0s);
        asm volatile("s_barrier" ::: "memory");
        asm volatile("s_waitcnt lgkmcnt(0)" ::: "memory");
        __builtin_amdgcn_sched_barrier(0);
        __builtin_amdgcn_s_setprio(1);
        MFMA4(4, a0) MFMA4(5, a1) MFMA4(6, a2) MFMA4(7, a3)
        __builtin_amdgcn_s_setprio(0);
        __builtin_amdgcn_sched_barrier(0);
        // Once per K-tile: allow this tile's 4 prefetch loads (t+2) to stay
        // in flight; guarantees tile t+1 (staged last K-tile) has landed.
        asm volatile("s_waitcnt vmcnt(4)" ::: "memory");
        asm volatile("s_barrier" ::: "memory");

        r  = (r  == 2) ? 0 : r  + 1;
        r2 = (r2 == 2) ? 0 : r2 + 1;
    }
    // Drain remaining DMA before the block can retire (LDS dealloc safety).
    asm volatile("s_waitcnt vmcnt(0)" ::: "memory");

    // Epilogue: C/D layout col = lane&15, row = (lane>>4)*4 + v (m89/m91).
    const int row0 = bm * BM + wm * 128 + ((lane >> 4) << 2);
    const int col0 = bn * BN + wn * 64 + lr;
#pragma unroll
    for (int ni = 0; ni < 4; ++ni) {
        const int col = col0 + ni * 16;
        const float bv = bias[col];
#pragma unroll
        for (int mi = 0; mi < 8; ++mi) {
#pragma unroll
            for (int v = 0; v < 4; ++v) {
                C[(size_t)(row0 + mi * 16 + v) * N_DIM + col] = acc[mi][ni][v] + bv;
            }
        }
    }
}

extern "C" void kernel_launch(void* const* d_in, const int* in_sizes, int n_in,
                              void* d_out, int out_size, void* d_ws, size_t ws_size,
                              hipStream_t stream) {
    const float* x    = (const float*)d_in[0];   // [4,2048,4096] f32
    const int*   wq   = (const int*)d_in[1];     // [11008,4096] int32 in 0..15
    const float* am   = (const float*)d_in[2];   // [11008,64] f32
    const float* bias = (const float*)d_in[3];   // [11008] f32
    float* out = (float*)d_out;                  // [4,2048,11008] f32

    const size_t w_elems = (size_t)N_DIM * K_DIM;
    const size_t x_elems = (size_t)M_DIM * K_DIM;
    const size_t need = (w_elems + x_elems) * sizeof(unsigned short);
    if (ws_size < need) return;

    unsigned short* wbf = (unsigned short*)d_ws;
    unsigned short* xbf = wbf + w_elems;

    nf4_dequant_w<<<(int)(w_elems / 8 / 256), 256, 0, stream>>>(wq, am, wbf);
    x_to_bf16<<<(int)(x_elems / 8 / 256), 256, 0, stream>>>(x, xbf);

    const int grid = (M_DIM / BM) * (N_DIM / BN);   // 32 * 43 = 1376
    gemm256<<<grid, 512, 0, stream>>>(xbf, wbf, bias, out);
}

// Round 3
// 911.197 us; speedup vs baseline: 1.2554x; 1.0230x over previous
//
#include <hip/hip_runtime.h>
#include <hip/hip_bf16.h>
#include <stdint.h>

typedef __attribute__((ext_vector_type(8))) short short8;
typedef __attribute__((ext_vector_type(8))) unsigned short ushort8;
typedef __attribute__((ext_vector_type(4))) float f32x4;

#define K_DIM 4096
#define N_DIM 11008
#define M_DIM 8192
#define BM 256
#define BN 256
#define BK 32
#define TILES (K_DIM / BK)   // 128
#define NBUF 4               // prefetch depth 3

__constant__ float c_nf4[16] = {
    -1.0f, -0.6961928009986877f, -0.5250730514526367f, -0.39491748809814453f,
    -0.28444138169288635f, -0.18477343022823334f, -0.09105003625154495f, 0.0f,
    0.07958029955625534f, 0.16093020141124725f, 0.24611230194568634f,
    0.33791524171829224f, 0.44070982933044434f, 0.5626170039176941f,
    0.7229568362236023f, 1.0f};

__device__ __forceinline__ unsigned short f2bf(float f) {
    uint32_t u = __float_as_uint(f);
    u += 0x7fffu + ((u >> 16) & 1u);   // round-to-nearest-even (finite inputs)
    return (unsigned short)(u >> 16);
}

__global__ __launch_bounds__(256) void nf4_dequant_w(const int* __restrict__ q,
                                                     const float* __restrict__ absmax,
                                                     unsigned short* __restrict__ w) {
    __shared__ float lut[16];
    if (threadIdx.x < 16) lut[threadIdx.x] = c_nf4[threadIdx.x];
    __syncthreads();
    size_t t = (size_t)blockIdx.x * 256 + threadIdx.x;
    const int4* q4 = (const int4*)q;
    int4 qa = q4[2 * t];
    int4 qb = q4[2 * t + 1];
    float s = absmax[t >> 3];
    ushort8 o;
    o[0] = f2bf(lut[qa.x & 15] * s);
    o[1] = f2bf(lut[qa.y & 15] * s);
    o[2] = f2bf(lut[qa.z & 15] * s);
    o[3] = f2bf(lut[qa.w & 15] * s);
    o[4] = f2bf(lut[qb.x & 15] * s);
    o[5] = f2bf(lut[qb.y & 15] * s);
    o[6] = f2bf(lut[qb.z & 15] * s);
    o[7] = f2bf(lut[qb.w & 15] * s);
    ((ushort8*)w)[t] = o;
}

__global__ __launch_bounds__(256) void x_to_bf16(const float* __restrict__ x,
                                                 unsigned short* __restrict__ xb) {
    size_t t = (size_t)blockIdx.x * 256 + threadIdx.x;
    const float4* x4 = (const float4*)x;
    float4 a = x4[2 * t];
    float4 b = x4[2 * t + 1];
    ushort8 o;
    o[0] = f2bf(a.x); o[1] = f2bf(a.y); o[2] = f2bf(a.z); o[3] = f2bf(a.w);
    o[4] = f2bf(b.x); o[5] = f2bf(b.y); o[6] = f2bf(b.z); o[7] = f2bf(b.w);
    ((ushort8*)xb)[t] = o;
}

// Stage one 128-row half of a [256][32] bf16 tile: 512 threads x 16B, linear
// LDS dest (HW rule), XOR-swizzled GLOBAL source column (rule 21):
// LDS element (row, e) ends up holding global element (row, e ^ ((row&3)<<3)).
#define STAGE(gbase, region, j, k0)                                           \
  do {                                                                        \
    const int _row = (j) * 128 + (tid >> 2);                                  \
    const int _cp = tid & 3;                                                  \
    const int _col = ((_cp ^ (_row & 3)) << 3);                               \
    __builtin_amdgcn_global_load_lds(                                         \
        (const __attribute__((address_space(1))) void*)((gbase) +             \
            (size_t)_row * K_DIM + (k0) + _col),                              \
        (__attribute__((address_space(3))) void*)((region) +                  \
            ((j) * 512 + wave * 64) * 8),                                     \
        16, 0, 0);                                                            \
  } while (0)

#define MFMA4(mi_, Areg)                                                                  \
  acc[mi_][0] = __builtin_amdgcn_mfma_f32_16x16x32_bf16(Areg, b0, acc[mi_][0], 0, 0, 0);  \
  acc[mi_][1] = __builtin_amdgcn_mfma_f32_16x16x32_bf16(Areg, b1, acc[mi_][1], 0, 0, 0);  \
  acc[mi_][2] = __builtin_amdgcn_mfma_f32_16x16x32_bf16(Areg, b2, acc[mi_][2], 0, 0, 0);  \
  acc[mi_][3] = __builtin_amdgcn_mfma_f32_16x16x32_bf16(Areg, b3, acc[mi_][3], 0, 0, 0);

// 256x256 tile, BK=32, 8 waves (2M x 4N), quad-buffered LDS (prefetch 3),
// counted vmcnt(8), XOR-swizzled LDS. C = A * B^T + bias; bf16 in, f32 out.
__global__ __launch_bounds__(512, 2) void gemm256(const unsigned short* __restrict__ A,
                                                  const unsigned short* __restrict__ B,
                                                  const float* __restrict__ bias,
                                                  float* __restrict__ C) {
    __shared__ unsigned short As[NBUF][BM * BK];   // 4 x 16 KB
    __shared__ unsigned short Bs[NBUF][BN * BK];   // 4 x 16 KB -> 128 KB total

    const int tid  = threadIdx.x;
    const int wave = tid >> 6;
    const int lane = tid & 63;
    const int wm = wave >> 2;               // 0..1 -> 128-row slab
    const int wn = wave & 3;                // 0..3 -> 64-col slab
    const int lr = lane & 15;
    const int lk = (lane >> 4) << 3;        // 0,8,16,24
    const int sw = lk ^ ((lr & 3) << 3);    // swizzled read offset (per-lane const)

    // XCD-aware bijective swizzle: grid = 1376, 1376 % 8 == 0.
    const int nbn = N_DIM / BN;             // 43
    const int cpx = (int)gridDim.x >> 3;    // 172
    const int bid = (int)blockIdx.x;
    const int swz = (bid & 7) * cpx + (bid >> 3);
    const int bm = swz / nbn;
    const int bn = swz % nbn;

    const unsigned short* Ab = A + (size_t)bm * BM * K_DIM;
    const unsigned short* Bb = B + (size_t)bn * BN * K_DIM;

    f32x4 acc[8][4];
#pragma unroll
    for (int i = 0; i < 8; ++i)
#pragma unroll
        for (int j = 0; j < 4; ++j)
#pragma unroll
            for (int v = 0; v < 4; ++v) acc[i][j][v] = 0.0f;

    // Prologue: stage tiles 0,1,2 (12 loads/thread, per-tile issue order).
#pragma unroll
    for (int p = 0; p < 3; ++p) {
        STAGE(Ab, &As[p][0], 0, p * BK); STAGE(Bb, &Bs[p][0], 0, p * BK);
        STAGE(Ab, &As[p][0], 1, p * BK); STAGE(Bb, &Bs[p][0], 1, p * BK);
    }
    asm volatile("s_waitcnt vmcnt(8)" ::: "memory");   // tile 0 landed
    asm volatile("s_barrier" ::: "memory");

#pragma unroll 1
    for (int t = 0; t < TILES; ++t) {
        const int r  = t & (NBUF - 1);
        const int rw = (t + 3) & (NBUF - 1);
        int ts = t + 3; if (ts >= TILES) ts -= TILES;  // tail wrap: harmless garbage stage
        const int k0s = ts * BK;
        const unsigned short* Ar = &As[r][0];
        const unsigned short* Br = &Bs[r][0];
        unsigned short* Aw = &As[rw][0];
        unsigned short* Bw = &Bs[rw][0];

        // ---------------- phase 1: quadrant mi 0..3 ----------------
        short8 a0 = *(const short8*)(Ar + (wm * 128 +  0 + lr) * BK + sw);
        short8 a1 = *(const short8*)(Ar + (wm * 128 + 16 + lr) * BK + sw);
        short8 a2 = *(const short8*)(Ar + (wm * 128 + 32 + lr) * BK + sw);
        short8 a3 = *(const short8*)(Ar + (wm * 128 + 48 + lr) * BK + sw);
        short8 b0 = *(const short8*)(Br + (wn * 64 +  0 + lr) * BK + sw);
        short8 b1 = *(const short8*)(Br + (wn * 64 + 16 + lr) * BK + sw);
        short8 b2 = *(const short8*)(Br + (wn * 64 + 32 + lr) * BK + sw);
        short8 b3 = *(const short8*)(Br + (wn * 64 + 48 + lr) * BK + sw);
        STAGE(Ab, Aw, 0, k0s);
        STAGE(Bb, Bw, 0, k0s);
        asm volatile("s_barrier" ::: "memory");
        asm volatile("s_waitcnt lgkmcnt(0)" ::: "memory");
        __builtin_amdgcn_sched_barrier(0);
        __builtin_amdgcn_s_setprio(1);
        MFMA4(0, a0) MFMA4(1, a1) MFMA4(2, a2) MFMA4(3, a3)
        __builtin_amdgcn_s_setprio(0);
        __builtin_amdgcn_sched_barrier(0);
        asm volatile("s_barrier" ::: "memory");

        // ---------------- phase 2: quadrant mi 4..7 (reuse b0..b3) --
        a0 = *(const short8*)(Ar + (wm * 128 +  64 + lr) * BK + sw);
        a1 = *(const short8*)(Ar + (wm * 128 +  80 + lr) * BK + sw);
        a2 = *(const short8*)(Ar + (wm * 128 +  96 + lr) * BK + sw);
        a3 = *(const short8*)(Ar + (wm * 128 + 112 + lr) * BK + sw);
        STAGE(Ab, Aw, 1, k0s);
        STAGE(Bb, Bw, 1, k0s);
        asm volatile("s_barrier" ::: "memory");
        asm volatile("s_waitcnt lgkmcnt(0)" ::: "memory");
        __builtin_amdgcn_sched_barrier(0);
        __builtin_amdgcn_s_setprio(1);
        MFMA4(4, a0) MFMA4(5, a1) MFMA4(6, a2) MFMA4(7, a3)
        __builtin_amdgcn_s_setprio(0);
        __builtin_amdgcn_sched_barrier(0);
        // Counted wait, once per K-tile: keep this tile's 4 prefetch loads
        // (t+3) and last tile's 4 (t+2) in flight; older (t+1) have landed.
        asm volatile("s_waitcnt vmcnt(8)" ::: "memory");
        asm volatile("s_barrier" ::: "memory");
    }
    // Drain remaining DMA before block retire (LDS dealloc safety).
    asm volatile("s_waitcnt vmcnt(0)" ::: "memory");

    // Epilogue: C/D layout col = lane&15, row = (lane>>4)*4 + v (m89/m91).
    const int row0 = bm * BM + wm * 128 + ((lane >> 4) << 2);
    const int col0 = bn * BN + wn * 64 + lr;
#pragma unroll
    for (int ni = 0; ni < 4; ++ni) {
        const int col = col0 + ni * 16;
        const float bv = bias[col];
#pragma unroll
        for (int mi = 0; mi < 8; ++mi) {
#pragma unroll
            for (int v = 0; v < 4; ++v) {
                C[(size_t)(row0 + mi * 16 + v) * N_DIM + col] = acc[mi][ni][v] + bv;
            }
        }
    }
}

extern "C" void kernel_launch(void* const* d_in, const int* in_sizes, int n_in,
                              void* d_out, int out_size, void* d_ws, size_t ws_size,
                              hipStream_t stream) {
    const float* x    = (const float*)d_in[0];   // [4,2048,4096] f32
    const int*   wq   = (const int*)d_in[1];     // [11008,4096] int32 in 0..15
    const float* am   = (const float*)d_in[2];   // [11008,64] f32
    const float* bias = (const float*)d_in[3];   // [11008] f32
    float* out = (float*)d_out;                  // [4,2048,11008] f32

    const size_t w_elems = (size_t)N_DIM * K_DIM;
    const size_t x_elems = (size_t)M_DIM * K_DIM;
    const size_t need = (w_elems + x_elems) * sizeof(unsigned short);
    if (ws_size < need) return;

    unsigned short* wbf = (unsigned short*)d_ws;
    unsigned short* xbf = wbf + w_elems;

    nf4_dequant_w<<<(int)(w_elems / 8 / 256), 256, 0, stream>>>(wq, am, wbf);
    x_to_bf16<<<(int)(x_elems / 8 / 256), 256, 0, stream>>>(x, xbf);

    const int grid = (M_DIM / BM) * (N_DIM / BN);   // 32 * 43 = 1376
    gemm256<<<grid, 512, 0, stream>>>(xbf, wbf, bias, out);
}